// Round 5
// baseline (321.310 us; speedup 1.0000x reference)
//
#include <hip/hip_runtime.h>
#include <math.h>

#define NB 8
#define NC 3
#define NH 1024
#define NW 1024
#define EPS 1e-6f

#define BAND 128            // output cols per wave (float2 per lane)
#define CH 16               // output rows per wave
#define KSTEPS (CH + 10)    // 26 product rows per chunk
#define NCHUNK (NH / CH)    // 64
#define PADW 144            // 8 pad | 128 | 8 pad  (floats)
// waves: 8 batches * 8 bands * 64 chunks = 4096 -> 2048 blocks x 2 waves
// = 8 blocks/CU = 16 waves/CU (4/SIMD). Block's 2 waves = adjacent chunks
// (share 10 halo rows in L1); bid % 8 == band -> chunk-neighbors same XCD.

__global__ __launch_bounds__(128, 4)
void lcs_kernel(const float* __restrict__ x, const float* __restrict__ y,
                float* __restrict__ out) {
    __shared__ __align__(16) float P[2][3][PADW];   // 3456 B

    const int tid = threadIdx.x;
    const int l = tid & 63;
    const int w = __builtin_amdgcn_readfirstlane(tid >> 6);   // scalar wave id

    // bid = b*256 + cblk*8 + band ; wave chunk = 2*cblk + w
    const int bid   = blockIdx.x;
    const int b     = bid >> 8;
    const int rem   = bid & 255;
    const int band0 = (rem & 7) * BAND;
    const int r0    = ((rem >> 3) * 2 + w) * CH;

    const size_t chan = (size_t)NH * NW;
    const float* xb = x + (size_t)b * NC * chan;
    const float* yb = y + (size_t)b * NC * chan;

    // lane column offsets (loop-invariant) + edge masks folded to floats
    const int gc0 = band0 - 8 + 2 * l;
    const int gcE = band0 + 120 + 2 * l;              // lanes 0..7 only
    const float mm = (gc0 >= 0) ? 1.f : 0.f;
    const float me = (l < 8 && gcE + 1 <= NW - 1) ? 1.f : 0.f;
    const int o0 = (gc0 >= 0) ? gc0 : 0;
    const int oE = (me > 0.f) ? gcE : 0;

    float2 cur[12], nxt[12];
    auto ldrow = [&](int gr, float2* d) {
        const int rc = gr < 0 ? 0 : (gr > NH - 1 ? NH - 1 : gr);  // scalar clamp
        const size_t ro = (size_t)rc * NW;
        #pragma unroll
        for (int c = 0; c < 3; ++c) {
            const float* xr = xb + c * chan + ro;    // scalar base -> saddr form
            const float* yr = yb + c * chan + ro;
            d[c]     = *(const float2*)(xr + o0);
            d[3 + c] = *(const float2*)(yr + o0);
            d[6 + c] = *(const float2*)(xr + oE);
            d[9 + c] = *(const float2*)(yr + oE);
        }
    };

    ldrow(r0 - 5, cur);   // prime k=0

    float2 ring[3][11];
    #pragma unroll
    for (int p = 0; p < 3; ++p)
        #pragma unroll
        for (int s = 0; s < 11; ++s) ring[p][s] = make_float2(0.f, 0.f);
    float2 vs[3] = {make_float2(0.f,0.f), make_float2(0.f,0.f), make_float2(0.f,0.f)};

    for (int g = 0; g < 3; ++g) {                 // ceil(26/11)
        #pragma unroll
        for (int s = 0; s < 11; ++s) {            // unrolled -> static ring index
            const int k = g * 11 + s;
            if (k >= KSTEPS) continue;            // uniform (g==2, s>=4)

            // ---- prefetch next product row first: max time in flight ----
            if (k + 1 < KSTEPS) ldrow(r0 - 4 + k, nxt);

            // ---- channel-reduced products of current row ----
            float2 pxx = make_float2(0.f,0.f), pyy = pxx, pxy = pxx;
            float2 qxx = pxx, qyy = pxx, qxy = pxx;
            #pragma unroll
            for (int c = 0; c < 3; ++c) {
                const float2 xm = cur[c],   ym = cur[3+c];
                const float2 xe = cur[6+c], ye = cur[9+c];
                pxx.x += xm.x*xm.x; pxx.y += xm.y*xm.y;
                pyy.x += ym.x*ym.x; pyy.y += ym.y*ym.y;
                pxy.x += xm.x*ym.x; pxy.y += xm.y*ym.y;
                qxx.x += xe.x*xe.x; qxx.y += xe.y*xe.y;
                qyy.x += ye.x*ye.x; qyy.y += ye.y*ye.y;
                qxy.x += xe.x*ye.x; qxy.y += xe.y*ye.y;
            }
            const int gr = r0 - 5 + k;
            const float rmf = (gr >= 0 && gr < NH) ? 1.f : 0.f;   // scalar
            const float cmM = rmf * mm, cmE = rmf * me;
            pxx.x *= cmM; pxx.y *= cmM; pyy.x *= cmM; pyy.y *= cmM;
            pxy.x *= cmM; pxy.y *= cmM;
            qxx.x *= cmE; qxx.y *= cmE; qyy.x *= cmE; qyy.y *= cmE;
            qxy.x *= cmE; qxy.y *= cmE;

            ((float2*)&P[w][0][0])[l] = pxx;
            ((float2*)&P[w][1][0])[l] = pyy;
            ((float2*)&P[w][2][0])[l] = pxy;
            if (l < 8) {
                ((float2*)&P[w][0][0])[64 + l] = qxx;
                ((float2*)&P[w][1][0])[64 + l] = qyy;
                ((float2*)&P[w][2][0])[64 + l] = qxy;
            }
            __builtin_amdgcn_wave_barrier();   // same-wave LDS: order only

            // ---- horizontal 11-tap + vertical running sum (ring) ----
            #pragma unroll
            for (int p = 0; p < 3; ++p) {
                const float* Pp = &P[w][p][0];
                float2 t[7];
                #pragma unroll
                for (int j = 0; j < 7; ++j)
                    t[j] = *(const float2*)(Pp + 2*l + 2 + 2*j);
                float h0 = ((t[0].y + t[1].x) + (t[1].y + t[2].x))
                         + ((t[2].y + t[3].x) + (t[3].y + t[4].x))
                         + ((t[4].y + t[5].x) + t[5].y);
                float h1 = h0 - t[0].y + t[6].x;
                vs[p].x += h0 - ring[p][s].x;
                vs[p].y += h1 - ring[p][s].y;
                ring[p][s].x = h0;
                ring[p][s].y = h1;
            }
            __builtin_amdgcn_wave_barrier();   // reads above next step's writes

            // ---- emit ----
            if (k >= 10) {
                const int orow = r0 + k - 10;
                const float d0 = __builtin_amdgcn_sqrtf(vs[0].x) *
                                 __builtin_amdgcn_sqrtf(vs[1].x) + EPS;
                const float d1 = __builtin_amdgcn_sqrtf(vs[0].y) *
                                 __builtin_amdgcn_sqrtf(vs[1].y) + EPS;
                float2 o;
                o.x = vs[2].x * __builtin_amdgcn_rcpf(d0);
                o.y = vs[2].y * __builtin_amdgcn_rcpf(d1);
                *(float2*)(out + ((size_t)b * NH + orow) * NW + band0 + 2*l) = o;
            }

            if (k + 1 < KSTEPS) {
                #pragma unroll
                for (int i = 0; i < 12; ++i) cur[i] = nxt[i];
            }
        }
    }
}

extern "C" void kernel_launch(void* const* d_in, const int* in_sizes, int n_in,
                              void* d_out, int out_size, void* d_ws, size_t ws_size,
                              hipStream_t stream) {
    const float* x = (const float*)d_in[0];
    const float* y = (const float*)d_in[1];
    float* out = (float*)d_out;
    lcs_kernel<<<dim3(2048), dim3(128), 0, stream>>>(x, y, out);
}

// Round 6
// 259.114 us; speedup vs baseline: 1.2400x; 1.2400x over previous
//
#include <hip/hip_runtime.h>
#include <math.h>

#define NB 8
#define NC 3
#define NH 1024
#define NW 1024
#define EPS 1e-6f

#define BAND 128            // output cols per wave (float2 per lane)
#define CH 16               // output rows per wave
#define KSTEPS (CH + 10)    // 26 product rows per chunk
#define PADW 144            // 8 pad | 128 | 8 pad  (floats)
// 8 batches * 8 bands * 64 chunks = 4096 one-wave blocks -> 16 blocks/CU.
// No s_barrier in kernel => not barrier-slot limited; 96 VGPR => 4 waves/SIMD ok.
// bid%8 = band => chunk-neighbors (bid +/- 8) map to the same XCD (L2 halo reuse).

__global__ __launch_bounds__(64, 2)   // (64,2) proven: 96 VGPR, no spill (R4)
void lcs_kernel(const float* __restrict__ x, const float* __restrict__ y,
                float* __restrict__ out) {
    __shared__ __align__(16) float P[3][PADW];   // 1728 B, wave-private

    const int l   = threadIdx.x;                 // 0..63
    const int bid = blockIdx.x;
    const int b     = bid >> 9;                  // 8 batches
    const int rem   = bid & 511;                 // 8 bands * 64 chunks
    const int band0 = (rem & 7) * BAND;
    const int r0    = (rem >> 3) * CH;

    const size_t chan = (size_t)NH * NW;
    const float* xb = x + (size_t)b * NC * chan;
    const float* yb = y + (size_t)b * NC * chan;

    // lane column offsets (loop-invariant) + edge masks folded to floats
    const int gc0 = band0 - 8 + 2 * l;
    const int gcE = band0 + 120 + 2 * l;              // lanes 0..7 only
    const float mm = (gc0 >= 0) ? 1.f : 0.f;
    const float me = (l < 8 && gcE + 1 <= NW - 1) ? 1.f : 0.f;
    const int o0 = (gc0 >= 0) ? gc0 : 0;
    const int oE = (me > 0.f) ? gcE : 0;

    float2 cur[12], nxt[12];
    // d[0..2]=x main ch, d[3..5]=y main, d[6..8]=x extra, d[9..11]=y extra
    auto ldrow = [&](int gr, float2* d) {
        const int rc = gr < 0 ? 0 : (gr > NH - 1 ? NH - 1 : gr);  // scalar clamp
        const size_t ro = (size_t)rc * NW;
        #pragma unroll
        for (int c = 0; c < 3; ++c) {
            const float* xr = xb + c * chan + ro;    // scalar base -> saddr form
            const float* yr = yb + c * chan + ro;
            d[c]     = *(const float2*)(xr + o0);
            d[3 + c] = *(const float2*)(yr + o0);
            d[6 + c] = *(const float2*)(xr + oE);
            d[9 + c] = *(const float2*)(yr + oE);
        }
    };

    ldrow(r0 - 5, cur);   // prime k=0

    float2 ring[3][11];
    #pragma unroll
    for (int p = 0; p < 3; ++p)
        #pragma unroll
        for (int s = 0; s < 11; ++s) ring[p][s] = make_float2(0.f, 0.f);
    float2 vs[3] = {make_float2(0.f,0.f), make_float2(0.f,0.f), make_float2(0.f,0.f)};

    for (int g = 0; g < 3; ++g) {                 // ceil(26/11)
        #pragma unroll
        for (int s = 0; s < 11; ++s) {            // unrolled -> static ring index
            const int k = g * 11 + s;
            if (k >= KSTEPS) continue;            // uniform (g==2, s>=4)

            // ---- prefetch next product row first: max time in flight ----
            if (k + 1 < KSTEPS) ldrow(r0 - 4 + k, nxt);

            // ---- channel-reduced products of current row ----
            float2 pxx = make_float2(0.f,0.f), pyy = pxx, pxy = pxx;
            float2 qxx = pxx, qyy = pxx, qxy = pxx;
            #pragma unroll
            for (int c = 0; c < 3; ++c) {
                const float2 xm = cur[c],   ym = cur[3+c];
                const float2 xe = cur[6+c], ye = cur[9+c];
                pxx.x += xm.x*xm.x; pxx.y += xm.y*xm.y;
                pyy.x += ym.x*ym.x; pyy.y += ym.y*ym.y;
                pxy.x += xm.x*ym.x; pxy.y += xm.y*ym.y;
                qxx.x += xe.x*xe.x; qxx.y += xe.y*xe.y;
                qyy.x += ye.x*ye.x; qyy.y += ye.y*ye.y;
                qxy.x += xe.x*ye.x; qxy.y += xe.y*ye.y;
            }
            const int gr = r0 - 5 + k;
            const float rmf = (gr >= 0 && gr < NH) ? 1.f : 0.f;   // scalar
            const float cmM = rmf * mm, cmE = rmf * me;
            pxx.x *= cmM; pxx.y *= cmM; pyy.x *= cmM; pyy.y *= cmM;
            pxy.x *= cmM; pxy.y *= cmM;
            qxx.x *= cmE; qxx.y *= cmE; qyy.x *= cmE; qyy.y *= cmE;
            qxy.x *= cmE; qxy.y *= cmE;

            ((float2*)&P[0][0])[l] = pxx;
            ((float2*)&P[1][0])[l] = pyy;
            ((float2*)&P[2][0])[l] = pxy;
            if (l < 8) {
                ((float2*)&P[0][0])[64 + l] = qxx;
                ((float2*)&P[1][0])[64 + l] = qyy;
                ((float2*)&P[2][0])[64 + l] = qxy;
            }
            __builtin_amdgcn_wave_barrier();   // same-wave LDS: order only

            // ---- horizontal 11-tap + vertical running sum (ring) ----
            #pragma unroll
            for (int p = 0; p < 3; ++p) {
                const float* Pp = &P[p][0];
                float2 t[7];
                #pragma unroll
                for (int j = 0; j < 7; ++j)
                    t[j] = *(const float2*)(Pp + 2*l + 2 + 2*j);
                float h0 = ((t[0].y + t[1].x) + (t[1].y + t[2].x))
                         + ((t[2].y + t[3].x) + (t[3].y + t[4].x))
                         + ((t[4].y + t[5].x) + t[5].y);
                float h1 = h0 - t[0].y + t[6].x;
                vs[p].x += h0 - ring[p][s].x;
                vs[p].y += h1 - ring[p][s].y;
                ring[p][s].x = h0;
                ring[p][s].y = h1;
            }
            __builtin_amdgcn_wave_barrier();   // reads above next step's writes

            // ---- emit ----
            if (k >= 10) {
                const int orow = r0 + k - 10;
                const float d0 = __builtin_amdgcn_sqrtf(vs[0].x) *
                                 __builtin_amdgcn_sqrtf(vs[1].x) + EPS;
                const float d1 = __builtin_amdgcn_sqrtf(vs[0].y) *
                                 __builtin_amdgcn_sqrtf(vs[1].y) + EPS;
                float2 o;
                o.x = vs[2].x * __builtin_amdgcn_rcpf(d0);
                o.y = vs[2].y * __builtin_amdgcn_rcpf(d1);
                *(float2*)(out + ((size_t)b * NH + orow) * NW + band0 + 2*l) = o;
            }

            if (k + 1 < KSTEPS) {
                #pragma unroll
                for (int i = 0; i < 12; ++i) cur[i] = nxt[i];
            }
        }
    }
}

extern "C" void kernel_launch(void* const* d_in, const int* in_sizes, int n_in,
                              void* d_out, int out_size, void* d_ws, size_t ws_size,
                              hipStream_t stream) {
    const float* x = (const float*)d_in[0];
    const float* y = (const float*)d_in[1];
    float* out = (float*)d_out;
    lcs_kernel<<<dim3(4096), dim3(64), 0, stream>>>(x, y, out);
}